// Round 1
// baseline (881.564 us; speedup 1.0000x reference)
//
#include <hip/hip_runtime.h>
#include <hip/hip_bf16.h>

using short8 = __attribute__((ext_vector_type(8))) short;
using f32x4  = __attribute__((ext_vector_type(4))) float;

#define GLL16(g, l)                                                          \
  __builtin_amdgcn_global_load_lds(                                          \
      (const __attribute__((address_space(1))) void*)(g),                    \
      (__attribute__((address_space(3))) void*)(l), 16, 0, 0)

// ---------------------------------------------------------------------------
// Kernel 1: fused smooth-scale + block-128 fake quant, fp32 -> bf16
// Each 32-lane group handles one 128-elem quant block (4 elems/lane, float4).
// ---------------------------------------------------------------------------
__global__ __launch_bounds__(256) void quant_kernel(
    const float* __restrict__ x, const float* __restrict__ smooth,
    __hip_bfloat16* __restrict__ xq, int D) {
  int tid = threadIdx.x;
  size_t qb = (size_t)blockIdx.x * 8 + (tid >> 5);
  int l = tid & 31;
  size_t base = qb * 128 + (size_t)l * 4;
  const float4 v = *(const float4*)(x + base);
  int d = (int)(base & (size_t)(D - 1));  // D is power of two (4096)
  const float4 s = *(const float4*)(smooth + d);
  float y0 = v.x * s.x, y1 = v.y * s.y, y2 = v.z * s.z, y3 = v.w * s.w;
  float am = fmaxf(fmaxf(fabsf(y0), fabsf(y1)), fmaxf(fabsf(y2), fabsf(y3)));
#pragma unroll
  for (int off = 1; off < 32; off <<= 1)
    am = fmaxf(am, __shfl_xor(am, off, 64));
  float scale = fminf(fmaxf(am, 1e-12f) / 6.0f, 448.0f);
  float q0 = fminf(fmaxf(rintf(y0 / scale), -6.0f), 6.0f) * scale;
  float q1 = fminf(fmaxf(rintf(y1 / scale), -6.0f), 6.0f) * scale;
  float q2 = fminf(fmaxf(rintf(y2 / scale), -6.0f), 6.0f) * scale;
  float q3 = fminf(fmaxf(rintf(y3 / scale), -6.0f), 6.0f) * scale;
  union {
    __hip_bfloat16 h[4];
    uint2 u;
  } pk;
  pk.h[0] = __float2bfloat16(q0);
  pk.h[1] = __float2bfloat16(q1);
  pk.h[2] = __float2bfloat16(q2);
  pk.h[3] = __float2bfloat16(q3);
  *(uint2*)(xq + base) = pk.u;
}

// ---------------------------------------------------------------------------
// Kernel 2: W_eff = w_ternary + lora_b @ lora_a  (fp32 accum), cast to bf16.
// Block: 16 o-rows x 256 d-cols. lora_b tile staged in LDS; lora_a streamed
// (1 MB total, L2-resident).
// ---------------------------------------------------------------------------
__global__ __launch_bounds__(256) void wprep_kernel(
    const float* __restrict__ w, const float* __restrict__ la,
    const float* __restrict__ lb, __hip_bfloat16* __restrict__ weff, int Dk,
    int R) {
  __shared__ float lbs[16 * 64];
  int tid = threadIdx.x;
  int o0 = (blockIdx.x >> 4) * 16;
  int d = ((blockIdx.x & 15) << 8) + tid;
#pragma unroll
  for (int i = 0; i < 4; ++i) {
    int idx = tid + i * 256;  // idx = oo*64 + r
    lbs[idx] = lb[(size_t)(o0 + (idx >> 6)) * R + (idx & 63)];
  }
  __syncthreads();
  float acc[16];
#pragma unroll
  for (int oo = 0; oo < 16; ++oo) acc[oo] = 0.f;
  for (int r = 0; r < 64; ++r) {
    float av = la[(size_t)r * Dk + d];
#pragma unroll
    for (int oo = 0; oo < 16; ++oo) acc[oo] += lbs[oo * 64 + r] * av;
  }
#pragma unroll
  for (int oo = 0; oo < 16; ++oo) {
    size_t idx = (size_t)(o0 + oo) * Dk + d;
    weff[idx] = __float2bfloat16(w[idx] + acc[oo]);
  }
}

// ---------------------------------------------------------------------------
// Kernel 3: C[M][N] = A[M][K] * B[N][K]^T + bias   (bf16 MFMA, fp32 out)
// 128x128 tile, BK=32, 256 threads (4 waves 2x2), 4x4 16x16x32 frags/wave,
// global_load_lds width-16 staging, double-buffered LDS, 1 barrier/K-step.
// ---------------------------------------------------------------------------
#define BM 128
#define BN 128
#define BK 32

__global__ __launch_bounds__(256, 2) void gemm_kernel(
    const __hip_bfloat16* __restrict__ A, const __hip_bfloat16* __restrict__ B,
    const float* __restrict__ bias, float* __restrict__ C, int M, int N,
    int K) {
  __shared__ __hip_bfloat16 sA[2][BM * BK];
  __shared__ __hip_bfloat16 sB[2][BN * BK];

  int tid = threadIdx.x;
  int nwg = gridDim.x;
  int wg = blockIdx.x;
  // XCD-aware bijective swizzle (nwg % 8 == 0)
  int cpx = nwg >> 3;
  int swz = (wg & 7) * cpx + (wg >> 3);
  int ntn = N / BN;
  int tm = swz / ntn, tn = swz % ntn;
  size_t m0 = (size_t)tm * BM, n0 = (size_t)tn * BN;

  int wave = tid >> 6, lane = tid & 63;
  int wr = wave >> 1, wc = wave & 1;

  // staging: 256 lanes x 16B = 4KB per issue; 2 issues per 8KB tile
  int srow = tid >> 2;
  int scol = (tid & 3) * 8;
  const __hip_bfloat16* ga = A + (m0 + srow) * (size_t)K + scol;
  const __hip_bfloat16* gb = B + (n0 + srow) * (size_t)K + scol;
  char* lA = (char*)&sA[0][0] + wave * 1024;  // wave-uniform LDS base
  char* lB = (char*)&sB[0][0] + wave * 1024;

  f32x4 acc[4][4];
#pragma unroll
  for (int m = 0; m < 4; ++m)
#pragma unroll
    for (int n = 0; n < 4; ++n) acc[m][n] = (f32x4){0.f, 0.f, 0.f, 0.f};

  int nk = K / BK;

  // prologue: stage tile 0 into buf 0
  GLL16(ga, lA);
  GLL16(ga + 64 * (size_t)K, lA + 4096);
  GLL16(gb, lB);
  GLL16(gb + 64 * (size_t)K, lB + 4096);
  __syncthreads();

  int lr = lane & 15;
  int lk = (lane >> 4) * 8;
  const __hip_bfloat16* rA = &sA[0][0] + (wr * 64 + lr) * BK + lk;
  const __hip_bfloat16* rB = &sB[0][0] + (wc * 64 + lr) * BK + lk;

  for (int kt = 0; kt < nk; ++kt) {
    int cur = kt & 1, nxt = cur ^ 1;
    if (kt + 1 < nk) {
      const __hip_bfloat16* ga2 = ga + (size_t)(kt + 1) * BK;
      const __hip_bfloat16* gb2 = gb + (size_t)(kt + 1) * BK;
      GLL16(ga2, lA + nxt * 8192);
      GLL16(ga2 + 64 * (size_t)K, lA + nxt * 8192 + 4096);
      GLL16(gb2, lB + nxt * 8192);
      GLL16(gb2 + 64 * (size_t)K, lB + nxt * 8192 + 4096);
    }
    short8 af[4], bf[4];
#pragma unroll
    for (int m = 0; m < 4; ++m)
      af[m] = *(const short8*)(rA + cur * 4096 + m * 16 * BK);
#pragma unroll
    for (int n = 0; n < 4; ++n)
      bf[n] = *(const short8*)(rB + cur * 4096 + n * 16 * BK);
#pragma unroll
    for (int m = 0; m < 4; ++m)
#pragma unroll
      for (int n = 0; n < 4; ++n)
        acc[m][n] =
            __builtin_amdgcn_mfma_f32_16x16x32_bf16(af[m], bf[n], acc[m][n], 0, 0, 0);
    __syncthreads();
  }

  // epilogue: C/D layout col=lane&15, row=(lane>>4)*4+reg  [verified m89/m91]
  int orow = (int)m0 + wr * 64 + (lane >> 4) * 4;
  int ocol = (int)n0 + wc * 64 + (lane & 15);
#pragma unroll
  for (int n = 0; n < 4; ++n) {
    float bv = bias[ocol + n * 16];
#pragma unroll
    for (int m = 0; m < 4; ++m) {
#pragma unroll
      for (int r = 0; r < 4; ++r)
        C[(size_t)(orow + m * 16 + r) * N + ocol + n * 16] = acc[m][n][r] + bv;
    }
  }
}

// ---------------------------------------------------------------------------
extern "C" void kernel_launch(void* const* d_in, const int* in_sizes, int n_in,
                              void* d_out, int out_size, void* d_ws,
                              size_t ws_size, hipStream_t stream) {
  const float* x = (const float*)d_in[0];
  const float* w = (const float*)d_in[1];
  const float* smooth = (const float*)d_in[2];
  const float* la = (const float*)d_in[3];
  const float* lb = (const float*)d_in[4];
  const float* bias = (const float*)d_in[5];
  float* out = (float*)d_out;

  const int K = in_sizes[2];              // D_IN  = 4096
  const int N = in_sizes[5];              // D_OUT = 4096
  const int M = in_sizes[0] / K;          // B*S   = 16384
  const int R = in_sizes[3] / K;          // 64

  __hip_bfloat16* xq = (__hip_bfloat16*)d_ws;
  __hip_bfloat16* weff = xq + (size_t)M * K;

  // 1) fake-quant activations -> bf16
  {
    size_t qblocks = ((size_t)M * K) / 128;
    int blocks = (int)(qblocks / 8);
    quant_kernel<<<blocks, 256, 0, stream>>>(x, smooth, xq, K);
  }
  // 2) W_eff = w + lora_b @ lora_a -> bf16
  {
    int blocks = (N / 16) * (K / 256);
    wprep_kernel<<<blocks, 256, 0, stream>>>(w, la, lb, weff, K, R);
  }
  // 3) main GEMM + bias
  {
    int blocks = (M / BM) * (N / BN);
    gemm_kernel<<<blocks, 256, 0, stream>>>(xq, weff, bias, out, M, N, K);
  }
}

// Round 2
// 634.222 us; speedup vs baseline: 1.3900x; 1.3900x over previous
//
#include <hip/hip_runtime.h>
#include <hip/hip_bf16.h>

using short8 = __attribute__((ext_vector_type(8))) short;
using f32x4  = __attribute__((ext_vector_type(4))) float;

#define GLL16(g, l)                                                          \
  __builtin_amdgcn_global_load_lds(                                          \
      (const __attribute__((address_space(1))) void*)(g),                    \
      (__attribute__((address_space(3))) void*)(l), 16, 0, 0)

// ---------------------------------------------------------------------------
// Kernel 1: fused smooth-scale + block-128 fake quant, fp32 -> bf16
// ---------------------------------------------------------------------------
__global__ __launch_bounds__(256) void quant_kernel(
    const float* __restrict__ x, const float* __restrict__ smooth,
    __hip_bfloat16* __restrict__ xq, int D) {
  int tid = threadIdx.x;
  size_t qb = (size_t)blockIdx.x * 8 + (tid >> 5);
  int l = tid & 31;
  size_t base = qb * 128 + (size_t)l * 4;
  const float4 v = *(const float4*)(x + base);
  int d = (int)(base & (size_t)(D - 1));
  const float4 s = *(const float4*)(smooth + d);
  float y0 = v.x * s.x, y1 = v.y * s.y, y2 = v.z * s.z, y3 = v.w * s.w;
  float am = fmaxf(fmaxf(fabsf(y0), fabsf(y1)), fmaxf(fabsf(y2), fabsf(y3)));
#pragma unroll
  for (int off = 1; off < 32; off <<= 1)
    am = fmaxf(am, __shfl_xor(am, off, 64));
  float scale = fminf(fmaxf(am, 1e-12f) / 6.0f, 448.0f);
  float q0 = fminf(fmaxf(rintf(y0 / scale), -6.0f), 6.0f) * scale;
  float q1 = fminf(fmaxf(rintf(y1 / scale), -6.0f), 6.0f) * scale;
  float q2 = fminf(fmaxf(rintf(y2 / scale), -6.0f), 6.0f) * scale;
  float q3 = fminf(fmaxf(rintf(y3 / scale), -6.0f), 6.0f) * scale;
  union {
    __hip_bfloat16 h[4];
    uint2 u;
  } pk;
  pk.h[0] = __float2bfloat16(q0);
  pk.h[1] = __float2bfloat16(q1);
  pk.h[2] = __float2bfloat16(q2);
  pk.h[3] = __float2bfloat16(q3);
  *(uint2*)(xq + base) = pk.u;
}

// ---------------------------------------------------------------------------
// Kernel 2: W_eff = w_ternary + lora_b @ lora_a  (fp32 accum), cast to bf16.
// ---------------------------------------------------------------------------
__global__ __launch_bounds__(256) void wprep_kernel(
    const float* __restrict__ w, const float* __restrict__ la,
    const float* __restrict__ lb, __hip_bfloat16* __restrict__ weff, int Dk,
    int R) {
  __shared__ float lbs[16 * 64];
  int tid = threadIdx.x;
  int o0 = (blockIdx.x >> 4) * 16;
  int d = ((blockIdx.x & 15) << 8) + tid;
#pragma unroll
  for (int i = 0; i < 4; ++i) {
    int idx = tid + i * 256;
    lbs[idx] = lb[(size_t)(o0 + (idx >> 6)) * R + (idx & 63)];
  }
  __syncthreads();
  float acc[16];
#pragma unroll
  for (int oo = 0; oo < 16; ++oo) acc[oo] = 0.f;
  for (int r = 0; r < 64; ++r) {
    float av = la[(size_t)r * Dk + d];
#pragma unroll
    for (int oo = 0; oo < 16; ++oo) acc[oo] += lbs[oo * 64 + r] * av;
  }
#pragma unroll
  for (int oo = 0; oo < 16; ++oo) {
    size_t idx = (size_t)(o0 + oo) * Dk + d;
    weff[idx] = __float2bfloat16(w[idx] + acc[oo]);
  }
}

// ---------------------------------------------------------------------------
// Kernel 3: 256x256-tile 8-phase bf16 GEMM  (C = A * B^T + bias)
// 512 threads = 8 waves (2M x 4N); BK=64; 128 KiB LDS, 2 dbuf x {A,B} x 2
// halves of [128 rows][64 cols] bf16. Per-wave output 128x64 strided across
// halves so each phase is a global (A-half, B-half) quadrant.
// T2: colbyte ^= (row&7)<<4 swizzle (pre-swizzled global src, swizzled read).
// T3/T4: 8 phases, 1 half-tile staged per phase, vmcnt(6) only at P4/P8.
// T5: setprio(1) around each 16-MFMA cluster.
// ---------------------------------------------------------------------------
#define BM 256
#define BN 256
#define BKT 64

__global__ __launch_bounds__(512, 2) void gemm_kernel(
    const __hip_bfloat16* __restrict__ A, const __hip_bfloat16* __restrict__ B,
    const float* __restrict__ bias, float* __restrict__ C, int M, int N,
    int K) {
  __shared__ __attribute__((aligned(16))) char lds[131072];

  const int tid = threadIdx.x;
  const int wave = tid >> 6, lane = tid & 63;
  const int wr = wave >> 2, wc = wave & 3;
  const int lr = lane & 15;
  const int hi16 = (lane >> 4) * 16;
  const int swx = (lr & 7) << 4;

  // XCD-aware bijective swizzle (nwg % 8 == 0: 1024 blocks)
  const int nwg = gridDim.x;
  const int cpx = nwg >> 3;
  const int swzb = (blockIdx.x & 7) * cpx + (blockIdx.x >> 3);
  const int ntn = N / BN;
  const int tm = swzb / ntn, tn = swzb % ntn;
  const size_t m0 = (size_t)tm * BM, n0 = (size_t)tn * BN;

  // staging: per-thread pre-swizzled global source; linear wave-uniform LDS dest
  const int trow = tid >> 3;
  const int csw = ((tid & 7) ^ (trow & 7)) * 8;
  const __hip_bfloat16* baseA = A + (m0 + trow) * (size_t)K + csw;
  const __hip_bfloat16* baseB = B + (n0 + trow) * (size_t)K + csw;
  char* sbase = lds + wave * 1024;

  // ds_read bases (per-lane, swizzled on read)
  const char* rdA = lds + (wr * 64 + lr) * 128;
  const char* rdB = lds + 32768 + (wc * 32 + lr) * 128;

#define STAGE(d, ab, h, kt)                                                   \
  do {                                                                        \
    const __hip_bfloat16* _g = ((ab) ? baseB : baseA) +                       \
                               (size_t)((h) * 128) * K + (size_t)(kt) * BKT;  \
    char* _l = sbase + (d) * 65536 + (ab) * 32768 + (h) * 16384;              \
    GLL16(_g, _l);                                                            \
    GLL16(_g + 64 * (size_t)K, _l + 8192);                                    \
  } while (0)

#define READ_A(d, h)                                                          \
  _Pragma("unroll") for (int m = 0; m < 4; ++m)                               \
      _Pragma("unroll") for (int kk = 0; kk < 2; ++kk)                        \
          aF[m][kk] = *(const short8*)(rdA + (d) * 65536 + (h) * 16384 +      \
                                       m * 2048 + ((kk * 64 + hi16) ^ swx));

#define READ_B(d, g)                                                          \
  _Pragma("unroll") for (int n = 0; n < 2; ++n)                               \
      _Pragma("unroll") for (int kk = 0; kk < 2; ++kk)                        \
          bF[n][kk] = *(const short8*)(rdB + (d) * 65536 + (g) * 16384 +      \
                                       n * 2048 + ((kk * 64 + hi16) ^ swx));

#define MFMA16(h, g)                                                          \
  _Pragma("unroll") for (int kk = 0; kk < 2; ++kk)                            \
      _Pragma("unroll") for (int m = 0; m < 4; ++m)                           \
          _Pragma("unroll") for (int n = 0; n < 2; ++n)                       \
              acc[h][m][g][n] = __builtin_amdgcn_mfma_f32_16x16x32_bf16(      \
                  aF[m][kk], bF[n][kk], acc[h][m][g][n], 0, 0, 0);

#define SYNC_MFMA(h, g)                                                       \
  __builtin_amdgcn_s_barrier();                                               \
  asm volatile("s_waitcnt lgkmcnt(0)" ::: "memory");                          \
  __builtin_amdgcn_sched_barrier(0);                                          \
  __builtin_amdgcn_s_setprio(1);                                              \
  MFMA16(h, g);                                                               \
  __builtin_amdgcn_s_setprio(0);

#define VMW6()                                                                \
  asm volatile("s_waitcnt vmcnt(6)" ::: "memory");                            \
  __builtin_amdgcn_sched_barrier(0);

  short8 aF[4][2], bF[2][2];
  f32x4 acc[2][4][2][2];
#pragma unroll
  for (int h = 0; h < 2; ++h)
#pragma unroll
    for (int m = 0; m < 4; ++m)
#pragma unroll
      for (int g = 0; g < 2; ++g)
#pragma unroll
        for (int n = 0; n < 2; ++n) acc[h][m][g][n] = (f32x4){0.f, 0.f, 0.f, 0.f};

  const int NK = K / BKT;  // 64

  // prologue: K0 (all 4 halves) -> buf0; K1 {A-h0, B-h1, A-h1} -> buf1
  STAGE(0, 0, 0, 0);
  STAGE(0, 1, 1, 0);
  STAGE(0, 0, 1, 0);
  STAGE(0, 1, 0, 0);
  STAGE(1, 0, 0, 1);
  STAGE(1, 1, 1, 1);
  STAGE(1, 0, 1, 1);
  VMW6();
  __builtin_amdgcn_s_barrier();

  const int niter = NK / 2;  // 32
  for (int i = 0; i < niter; ++i) {
    const int k2 = (2 * i + 2 < NK) ? 2 * i + 2 : NK - 1;
    const int k3 = (2 * i + 3 < NK) ? 2 * i + 3 : NK - 1;
    // ---- K-tile 2i from buf0 ----
    // P1: quadrant (h0,g0)
    READ_A(0, 0);
    READ_B(0, 0);
    STAGE(1, 1, 0, 2 * i + 1);  // buf1.B-h0 for K-tile 2i+1
    SYNC_MFMA(0, 0);
    __builtin_amdgcn_s_barrier();
    // P2: (h0,g1)
    READ_B(0, 1);
    STAGE(0, 0, 0, k2);  // buf0.A-h0 <- K(2i+2)
    SYNC_MFMA(0, 1);
    __builtin_amdgcn_s_barrier();
    // P3: (h1,g1)
    READ_A(0, 1);
    STAGE(0, 1, 1, k2);  // buf0.B-h1
    SYNC_MFMA(1, 1);
    __builtin_amdgcn_s_barrier();
    // P4: (h1,g0)
    READ_B(0, 0);
    STAGE(0, 0, 1, k2);  // buf0.A-h1
    SYNC_MFMA(1, 0);
    VMW6();  // K-tile 2i+1 fully landed
    __builtin_amdgcn_s_barrier();
    // ---- K-tile 2i+1 from buf1 ----
    // P5: (h0,g0)
    READ_A(1, 0);
    READ_B(1, 0);
    STAGE(0, 1, 0, k2);  // buf0.B-h0
    SYNC_MFMA(0, 0);
    __builtin_amdgcn_s_barrier();
    // P6: (h0,g1)
    READ_B(1, 1);
    STAGE(1, 0, 0, k3);  // buf1.A-h0 <- K(2i+3)
    SYNC_MFMA(0, 1);
    __builtin_amdgcn_s_barrier();
    // P7: (h1,g1)
    READ_A(1, 1);
    STAGE(1, 1, 1, k3);  // buf1.B-h1
    SYNC_MFMA(1, 1);
    __builtin_amdgcn_s_barrier();
    // P8: (h1,g0)
    READ_B(1, 0);
    STAGE(1, 0, 1, k3);  // buf1.A-h1
    SYNC_MFMA(1, 0);
    VMW6();  // K-tile 2i+2 fully landed
    __builtin_amdgcn_s_barrier();
  }

  // epilogue: C/D layout col=lane&15, row=(lane>>4)*4+reg
#pragma unroll
  for (int h = 0; h < 2; ++h)
#pragma unroll
    for (int g = 0; g < 2; ++g)
#pragma unroll
      for (int n = 0; n < 2; ++n) {
        const int col = (int)n0 + g * 128 + wc * 32 + n * 16 + lr;
        const float bv = bias[col];
#pragma unroll
        for (int m = 0; m < 4; ++m) {
          const int row = (int)m0 + h * 128 + wr * 64 + m * 16 + (lane >> 4) * 4;
#pragma unroll
          for (int r = 0; r < 4; ++r)
            C[(size_t)(row + r) * N + col] = acc[h][m][g][n][r] + bv;
        }
      }
}

// ---------------------------------------------------------------------------
extern "C" void kernel_launch(void* const* d_in, const int* in_sizes, int n_in,
                              void* d_out, int out_size, void* d_ws,
                              size_t ws_size, hipStream_t stream) {
  const float* x = (const float*)d_in[0];
  const float* w = (const float*)d_in[1];
  const float* smooth = (const float*)d_in[2];
  const float* la = (const float*)d_in[3];
  const float* lb = (const float*)d_in[4];
  const float* bias = (const float*)d_in[5];
  float* out = (float*)d_out;

  const int K = in_sizes[2];      // 4096
  const int N = in_sizes[5];      // 4096
  const int M = in_sizes[0] / K;  // 16384
  const int R = in_sizes[3] / K;  // 64

  __hip_bfloat16* xq = (__hip_bfloat16*)d_ws;
  __hip_bfloat16* weff = xq + (size_t)M * K;

  {
    size_t qblocks = ((size_t)M * K) / 128;
    int blocks = (int)(qblocks / 8);
    quant_kernel<<<blocks, 256, 0, stream>>>(x, smooth, xq, K);
  }
  {
    int blocks = (N / 16) * (K / 256);
    wprep_kernel<<<blocks, 256, 0, stream>>>(w, la, lb, weff, K, R);
  }
  {
    int blocks = (M / BM) * (N / BN);
    gemm_kernel<<<blocks, 512, 0, stream>>>(xq, weff, bias, out, M, N, K);
  }
}